// Round 18
// baseline (212.566 us; speedup 1.0000x reference)
//
#include <hip/hip_runtime.h>
#include <hip/hip_bf16.h>
#include <stdint.h>
#include <type_traits>

// CausalSelfAttention: B=4 S=2048 D=1024 H=16 hd=64
// conv(x) -> QKV gemm (R10 + LDS-staged coalesced epilogue) -> V transpose
//   -> flash attn v5 (paired q-tiles, 32x32 mfma, in-register P, defer-max)
//   -> out-proj gemm (dbuf)

#define B_   4
#define S_   2048
#define D_   1024
#define H_   16
#define HD_  64
#define MTOK (B_ * S_)   // 8192
#define BK   32
#define QSCALE 0.18033688011112042f   // 0.125 * log2(e)

typedef __attribute__((ext_vector_type(8))) short bfx8;
typedef __attribute__((ext_vector_type(4))) float fx4;
typedef __attribute__((ext_vector_type(16))) float fx16;

#define MAX3(a,b,c) fmaxf(fmaxf(a,b),c)

static __device__ __forceinline__ unsigned short f2bf(float f) {
    union { float f; uint32_t u; } v{f};
    uint32_t u = v.u;
    u += 0x7fffu + ((u >> 16) & 1u);   // RNE
    return (unsigned short)(u >> 16);
}

static __device__ __forceinline__ uint32_t cvtpk(float lo, float hi) {
    uint32_t r;
    asm volatile("v_cvt_pk_bf16_f32 %0, %1, %2" : "=v"(r) : "v"(lo), "v"(hi));
    return r;
}

// v_permlane32_swap_b32 (distinct operands only — R8 bug)
static __device__ __forceinline__ void pswap(uint32_t& a, uint32_t& b) {
    asm volatile("v_permlane32_swap_b32 %0, %1" : "+v"(a), "+v"(b));
}

// global -> LDS direct DMA, 16B/lane; LDS dest = wave-uniform base + lane*16
static __device__ __forceinline__ void gll16(const unsigned short* g, const unsigned short* l) {
    typedef const __attribute__((address_space(1))) void* gp_t;
    typedef __attribute__((address_space(3))) void* lp_t;
    __builtin_amdgcn_global_load_lds((gp_t)(uintptr_t)g, (lp_t)(uint32_t)(uintptr_t)l, 16, 0, 0);
}

// ---------------- convert x f32 -> bf16 ----------------
__global__ void k_conv_x(const float* __restrict__ x, unsigned short* __restrict__ xb, int n8) {
    int i = blockIdx.x * blockDim.x + threadIdx.x;
    int stride = gridDim.x * blockDim.x;
    for (; i < n8; i += stride) {
        const float4* p = (const float4*)(x + (size_t)i * 8);
        float4 a = p[0], b = p[1];
        bfx8 o;
        o[0]=f2bf(a.x); o[1]=f2bf(a.y); o[2]=f2bf(a.z); o[3]=f2bf(a.w);
        o[4]=f2bf(b.x); o[5]=f2bf(b.y); o[6]=f2bf(b.z); o[7]=f2bf(b.w);
        *(bfx8*)(xb + (size_t)i * 8) = o;
    }
}

// ---------------- transpose W [K][N] f32 -> Wt [N][K] bf16 ----------------
__global__ void k_transpose_bf(const float* __restrict__ w, unsigned short* __restrict__ wt,
                               int K, int N) {
    int idx = blockIdx.x * blockDim.x + threadIdx.x;
    int total = N * (K / 8);
    if (idx >= total) return;
    int n  = idx % N;
    int k0 = (idx / N) * 8;
    bfx8 o;
#pragma unroll
    for (int j = 0; j < 8; ++j) o[j] = f2bf(w[(size_t)(k0 + j) * N + n]);
    *(bfx8*)(wt + (size_t)n * K + k0) = o;
}

// ---------------- V transpose: Vw [bh][s][64] -> Vt [bh][64][s] ----------------
__global__ void k_transpose_v(const unsigned short* __restrict__ Vw,
                              unsigned short* __restrict__ Vt) {
    __shared__ unsigned short lds[64][72];
    const int bg = blockIdx.x;            // 2048 = 64 bh x 32 s-tiles
    const int bh = bg >> 5;
    const int st = (bg & 31) * 64;
    const int t = threadIdx.x;
#pragma unroll
    for (int j = 0; j < 2; ++j) {
        int c = t + 256 * j;
        int row = c >> 3, q = c & 7;
        *(bfx8*)&lds[row][q * 8] = *(const bfx8*)&Vw[((size_t)bh * S_ + st + row) * HD_ + q * 8];
    }
    __syncthreads();
#pragma unroll
    for (int j = 0; j < 2; ++j) {
        int c = t + 256 * j;
        int d = c >> 3, q = c & 7;
        bfx8 o;
#pragma unroll
        for (int e = 0; e < 8; ++e) o[e] = lds[q * 8 + e][d];
        *(bfx8*)&Vt[((size_t)bh * HD_ + d) * S_ + st + q * 8] = o;
    }
}

// ---------------- QKV GEMM: [8192,1024] x [1024,3072], BK=32, swapped mfma ----------------
// R10 mainloop + LDS-staged coalesced epilogue (SH reused after K-loop).
__launch_bounds__(256)
__global__ void k_gemm_qkv(const unsigned short* __restrict__ A,
                           const unsigned short* __restrict__ Bt,
                           const float* __restrict__ bias,
                           unsigned short* __restrict__ Qw,
                           unsigned short* __restrict__ Kw,
                           unsigned short* __restrict__ Vw) {
    __shared__ unsigned short SH[2 * 128 * BK];   // Al|Bl (16KB); epilogue: 64x128 staging
    unsigned short* Al = SH;
    unsigned short* Bl = SH + 128 * BK;
    const int wg = blockIdx.x;
    const int lin = (wg & 7) * 192 + (wg >> 3);
    const int ny = lin / 24, nx = lin - ny * 24;
    const int m0 = ny * 128;
    const int n0 = nx * 128;
    const int t = threadIdx.x;
    const int w = t >> 6, l = t & 63;
    const int wr = w >> 1, wc = w & 1;
    const int lr = l & 15, lg = l >> 4;
    const int srow = l >> 2;
    const int scol = (l & 3) * 8;
    fx4 acc[4][4] = {};

    for (int k0 = 0; k0 < D_; k0 += BK) {
        __syncthreads();
#pragma unroll
        for (int j = 0; j < 2; ++j) {
            int rb = j * 64 + w * 16;
            gll16(&A [(size_t)(m0 + rb + srow) * D_ + k0 + scol], &Al[rb * BK]);
            gll16(&Bt[(size_t)(n0 + rb + srow) * D_ + k0 + scol], &Bl[rb * BK]);
        }
        __syncthreads();
        bfx8 af[4], bf[4];
#pragma unroll
        for (int i = 0; i < 4; ++i) af[i] = *(const bfx8*)&Al[(wr * 64 + i * 16 + lr) * BK + lg * 8];
#pragma unroll
        for (int i = 0; i < 4; ++i) bf[i] = *(const bfx8*)&Bl[(wc * 64 + i * 16 + lr) * BK + lg * 8];
#pragma unroll
        for (int mi = 0; mi < 4; ++mi)
#pragma unroll
            for (int ni = 0; ni < 4; ++ni)
                acc[mi][ni] = __builtin_amdgcn_mfma_f32_16x16x32_bf16(bf[ni], af[mi], acc[mi][ni], 0, 0, 0);
    }

    // ---- epilogue: bias+scale+pack into LDS (swizzled), read back, full-line stores ----
    const int mat = n0 >> 10;                  // uniform per block
    unsigned short* dst = (mat == 0) ? Qw : (mat == 1) ? Kw : Vw;
    const float sc = (mat == 0) ? QSCALE : 1.0f;
    float4 bv[4];
#pragma unroll
    for (int ni = 0; ni < 4; ++ni) bv[ni] = *(const float4*)&bias[n0 + wc * 64 + ni * 16 + lg * 4];

    __syncthreads();                           // all LDS frag reads complete
#pragma unroll
    for (int mh = 0; mh < 2; ++mh) {
        if (wr == mh) {
#pragma unroll
            for (int mi = 0; mi < 4; ++mi) {
                const int row = mi * 16 + lr;  // 0..63 within the staged half
#pragma unroll
                for (int ni = 0; ni < 4; ++ni) {
                    fx4 v = acc[mi][ni];
                    uint2 u;
                    u.x = cvtpk((v[0] + bv[ni].x) * sc, (v[1] + bv[ni].y) * sc);
                    u.y = cvtpk((v[2] + bv[ni].z) * sc, (v[3] + bv[ni].w) * sc);
                    const int colb = wc * 128 + ni * 32 + lg * 8;   // byte col (8B aligned)
                    *(uint2*)((char*)SH + row * 256 + (colb ^ ((row & 7) << 4))) = u;
                }
            }
        }
        __syncthreads();
        {
            const int row = t >> 2, seg = t & 3;   // 64 rows x 4 x 64B segments
            const int m = m0 + mh * 64 + row;
            const int b = m >> 11, s = m & 2047;
            const int ncol = n0 + seg * 32;
            const int h = (ncol & 1023) >> 6, dd = ncol & 63;
            unsigned short* g = &dst[((size_t)(b * H_ + h) * S_ + s) * HD_ + dd];
#pragma unroll
            for (int c = 0; c < 4; ++c) {
                uint4 q = *(uint4*)((char*)SH + row * 256 + ((seg * 64 + c * 16) ^ ((row & 7) << 4)));
                *(uint4*)((char*)g + c * 16) = q;
            }
        }
        __syncthreads();
    }
}

// ---------------- flash attention v5 (32x32 mfma, in-register P, end-combined lsum) ----------------
// 8 waves: w0-3 = big tile (15-pi), w4-7 = small tile (pi); 32 q-rows/wave.
__launch_bounds__(512, 4)
__global__ void k_attn(const unsigned short* __restrict__ Qw,
                       const unsigned short* __restrict__ Kw,
                       const unsigned short* __restrict__ Vt,
                       unsigned short* __restrict__ Ob) {
    __shared__ unsigned short Sh[4][64 * 64];   // [0,1]=K dbuf, [2,3]=V dbuf; rows 128B XOR-swizzled
    const int wg = blockIdx.x;                  // 512
    const int xcd = wg & 7, ix = wg >> 3;
    const int bh = xcd * 8 + (ix >> 3);
    const int pi = ix & 7;
    const int t = threadIdx.x;
    const int w = t >> 6, l = t & 63;
    const int lq = l & 31, hi = l >> 5;
    const int tile = (w < 4) ? (15 - pi) : pi;
    const int qr = tile * 128 + (w & 3) * 32;
    const int NT = 32 - 2 * pi;                 // always even

    const unsigned short* Qp = Qw + (size_t)bh * S_ * HD_;
    const unsigned short* Kp = Kw + (size_t)bh * S_ * HD_;
    const unsigned short* Vp = Vt + (size_t)bh * HD_ * S_;

    bfx8 qf[4];
#pragma unroll
    for (int kb = 0; kb < 4; ++kb)
        qf[kb] = *(const bfx8*)&Qp[(size_t)(qr + lq) * HD_ + kb * 16 + hi * 8];

    fx16 oacc[2] = {};
    float mrow = -1e30f, lsum = 0.f;            // own-half sum; combined once at end

    const int sid0 = t, sid1 = t + 512;
    const int srow0 = (sid0 & 511) >> 3, sq0 = sid0 & 7;
    const int srow1 = (sid1 & 511) >> 3, sq1 = sid1 & 7;
    const int soff0 = srow0 * 128 + ((sq0 * 16) ^ ((srow0 & 7) << 4));
    const int soff1 = srow1 * 128 + ((sq1 * 16) ^ ((srow1 & 7) << 4));

    auto step = [&](auto bufc, int tkv) {
        constexpr int BUF = decltype(bufc)::value;
        const int kv0 = tkv * 64;
        const bool pre = (tkv + 1 < NT);
        bfx8 sreg0, sreg1;
        if (pre) {
            const int kn = kv0 + 64;
            sreg0 = *(const bfx8*)&Kp[(size_t)(kn + srow0) * HD_ + sq0 * 8];
            sreg1 = *(const bfx8*)&Vp[(size_t)srow1 * S_ + kn + sq1 * 8];
        }
        if (kv0 <= qr + 31) {
            const char* Kb = (const char*)&Sh[BUF][0];
            const char* Vb = (const char*)&Sh[2 + BUF][0];
            const int sw = (lq & 7) << 4;
            fx16 s0 = {}, s1 = {};
            __builtin_amdgcn_s_setprio(1);
#pragma unroll
            for (int kb = 0; kb < 4; ++kb) {
                const int cb = kb * 32 + hi * 16;
                bfx8 k0 = *(const bfx8*)(Kb + lq * 128 + (cb ^ sw));
                bfx8 k1 = *(const bfx8*)(Kb + (32 + lq) * 128 + (cb ^ sw));
                s0 = __builtin_amdgcn_mfma_f32_32x32x16_bf16(k0, qf[kb], s0, 0, 0, 0);
                s1 = __builtin_amdgcn_mfma_f32_32x32x16_bf16(k1, qf[kb], s1, 0, 0, 0);
            }
            __builtin_amdgcn_s_setprio(0);
            if (kv0 + 63 > qr) {
                const int qrel = qr + lq - kv0;
#pragma unroll
                for (int r = 0; r < 16; ++r) {
                    const int kvo = (r & 3) + 8 * (r >> 2) + 4 * hi;
                    if (kvo > qrel)      s0[r] = -1e30f;
                    if (kvo + 32 > qrel) s1[r] = -1e30f;
                }
            }
            float a0 = MAX3(s0[0], s0[1], s0[2]);
            float a1 = MAX3(s0[3], s0[4], s0[5]);
            float a2 = MAX3(s0[6], s0[7], s0[8]);
            float a3 = MAX3(s0[9], s0[10], s0[11]);
            float a4 = MAX3(s0[12], s0[13], s0[14]);
            float a5 = MAX3(s0[15], s1[0], s1[1]);
            float a6 = MAX3(s1[2], s1[3], s1[4]);
            float a7 = MAX3(s1[5], s1[6], s1[7]);
            float a8 = MAX3(s1[8], s1[9], s1[10]);
            float a9 = MAX3(s1[11], s1[12], s1[13]);
            float aA = fmaxf(s1[14], s1[15]);
            float b0 = MAX3(a0, a1, a2);
            float b1 = MAX3(a3, a4, a5);
            float b2 = MAX3(a6, a7, a8);
            float b3 = fmaxf(a9, aA);
            float mx = MAX3(fmaxf(b0, b1), b2, b3);
            mx = fmaxf(mx, __shfl_xor(mx, 32));    // partners share mx -> identical al
            if (!__all(mx <= mrow + 8.f)) {
                const float mnew = fmaxf(mrow, mx);
                const float al = exp2f(mrow - mnew);
                mrow = mnew;
#pragma unroll
                for (int r = 0; r < 16; ++r) { oacc[0][r] *= al; oacc[1][r] *= al; }
                lsum *= al;
            }
            uint32_t pk0[8], pk1[8];
            float ps = 0.f;
#pragma unroll
            for (int j = 0; j < 8; ++j) {
                float p0 = exp2f(s0[2 * j] - mrow), p1 = exp2f(s0[2 * j + 1] - mrow);
                float p2 = exp2f(s1[2 * j] - mrow), p3 = exp2f(s1[2 * j + 1] - mrow);
                ps += (p0 + p1) + (p2 + p3);
                pk0[j] = cvtpk(p0, p1);
                pk1[j] = cvtpk(p2, p3);
            }
            lsum += ps;                            // own-half only; combine at end
            __builtin_amdgcn_s_setprio(1);
#pragma unroll
            for (int sl = 0; sl < 4; ++sl) {
                const uint32_t* pk = (sl < 2) ? pk0 : pk1;
                const int s = sl & 1;
                uint32_t w0 = pk[4 * s], w1 = pk[4 * s + 1], w2 = pk[4 * s + 2], w3 = pk[4 * s + 3];
                pswap(w0, w2);
                pswap(w1, w3);
                union { uint32_t u[4]; bfx8 v; } pf;
                pf.u[0] = w0; pf.u[1] = w1; pf.u[2] = w2; pf.u[3] = w3;
                const int cb = sl * 32 + hi * 16;
                bfx8 v0 = *(const bfx8*)(Vb + lq * 128 + (cb ^ sw));
                bfx8 v1 = *(const bfx8*)(Vb + (32 + lq) * 128 + (cb ^ sw));
                oacc[0] = __builtin_amdgcn_mfma_f32_32x32x16_bf16(v0, pf.v, oacc[0], 0, 0, 0);
                oacc[1] = __builtin_amdgcn_mfma_f32_32x32x16_bf16(v1, pf.v, oacc[1], 0, 0, 0);
            }
            __builtin_amdgcn_s_setprio(0);
        }
        if (pre) {
            *(bfx8*)((char*)&Sh[BUF ^ 1][0] + soff0) = sreg0;
            *(bfx8*)((char*)&Sh[2 + (BUF ^ 1)][0] + soff1) = sreg1;
        }
    };

    {
        bfx8 s0 = *(const bfx8*)&Kp[(size_t)srow0 * HD_ + sq0 * 8];
        bfx8 s1 = *(const bfx8*)&Vp[(size_t)srow1 * S_ + sq1 * 8];
        *(bfx8*)((char*)&Sh[0][0] + soff0) = s0;
        *(bfx8*)((char*)&Sh[2][0] + soff1) = s1;
    }
    __syncthreads();

    for (int tkv = 0; tkv < NT; tkv += 2) {
        step(std::integral_constant<int, 0>{}, tkv);
        __syncthreads();
        step(std::integral_constant<int, 1>{}, tkv + 1);
        __syncthreads();
    }

    lsum += __shfl_xor(lsum, 32);               // combine halves once
    const int b = bh >> 4, h = bh & 15;
    const float iv = __builtin_amdgcn_rcpf(lsum);
    unsigned short* orow = Ob + ((size_t)b * S_ + qr + lq) * D_ + h * 64;
#pragma unroll
    for (int db = 0; db < 2; ++db)
#pragma unroll
        for (int rq = 0; rq < 4; ++rq) {
            uint2 u;
            u.x = cvtpk(oacc[db][rq * 4 + 0] * iv, oacc[db][rq * 4 + 1] * iv);
            u.y = cvtpk(oacc[db][rq * 4 + 2] * iv, oacc[db][rq * 4 + 3] * iv);
            *(uint2*)&orow[db * 32 + rq * 8 + hi * 4] = u;
        }
}

// ---------------- out-proj GEMM: [8192,1024] x [1024,1024] + bias, f32 out, dbuf ----------------
__launch_bounds__(256)
__global__ void k_gemm_proj(const unsigned short* __restrict__ A,
                            const unsigned short* __restrict__ Bt,
                            const float* __restrict__ bias,
                            float* __restrict__ out) {
    __shared__ unsigned short Al[2][128 * BK];
    __shared__ unsigned short Bl[2][128 * BK];
    const int wg = blockIdx.x;                 // 512 blocks: 8 n x 64 m
    const int lin = (wg & 7) * 64 + (wg >> 3);
    const int ny = lin >> 3, nx = lin & 7;
    const int m0 = ny * 128;
    const int n0 = nx * 128;
    const int t = threadIdx.x;
    const int w = t >> 6, l = t & 63;
    const int wr = w >> 1, wc = w & 1;
    const int lr = l & 15, lg = l >> 4;
    const int srow = l >> 2;
    const int scol = (l & 3) * 8;
    fx4 acc[4][4] = {};

    auto stage = [&](int k0, int buf) {
#pragma unroll
        for (int j = 0; j < 2; ++j) {
            int rb = j * 64 + w * 16;
            gll16(&A [(size_t)(m0 + rb + srow) * D_ + k0 + scol], &Al[buf][rb * BK]);
            gll16(&Bt[(size_t)(n0 + rb + srow) * D_ + k0 + scol], &Bl[buf][rb * BK]);
        }
    };
    auto compute = [&](auto bufc) {
        constexpr int BUF = decltype(bufc)::value;
        bfx8 af[4], bf[4];
#pragma unroll
        for (int i = 0; i < 4; ++i) af[i] = *(const bfx8*)&Al[BUF][(wr * 64 + i * 16 + lr) * BK + lg * 8];
#pragma unroll
        for (int i = 0; i < 4; ++i) bf[i] = *(const bfx8*)&Bl[BUF][(wc * 64 + i * 16 + lr) * BK + lg * 8];
#pragma unroll
        for (int mi = 0; mi < 4; ++mi)
#pragma unroll
            for (int ni = 0; ni < 4; ++ni)
                acc[mi][ni] = __builtin_amdgcn_mfma_f32_16x16x32_bf16(bf[ni], af[mi], acc[mi][ni], 0, 0, 0);
    };

    stage(0, 0);
    __syncthreads();
    for (int k0 = 0; k0 < D_; k0 += 2 * BK) {
        if (k0 + BK < D_) stage(k0 + BK, 1);
        compute(std::integral_constant<int, 0>{});
        __syncthreads();
        if (k0 + 2 * BK < D_) stage(k0 + 2 * BK, 0);
        compute(std::integral_constant<int, 1>{});
        __syncthreads();
    }
#pragma unroll
    for (int ni = 0; ni < 4; ++ni) {
        const int nn = n0 + wc * 64 + ni * 16 + lg * 4;
        const float4 bv = *(const float4*)&bias[nn];
#pragma unroll
        for (int mi = 0; mi < 4; ++mi) {
            const int m = m0 + wr * 64 + mi * 16 + lr;
            fx4 v = acc[mi][ni];
            float4 o; o.x = v[0] + bv.x; o.y = v[1] + bv.y; o.z = v[2] + bv.z; o.w = v[3] + bv.w;
            *(float4*)&out[(size_t)m * D_ + nn] = o;
        }
    }
}

extern "C" void kernel_launch(void* const* d_in, const int* in_sizes, int n_in,
                              void* d_out, int out_size, void* d_ws, size_t ws_size,
                              hipStream_t stream) {
    const float* x     = (const float*)d_in[0];
    const float* w_qkv = (const float*)d_in[1];
    const float* b_qkv = (const float*)d_in[2];
    const float* w_out = (const float*)d_in[3];
    const float* b_out = (const float*)d_in[4];
    float* out = (float*)d_out;

    unsigned short* xb    = (unsigned short*)d_ws;          // 8192*1024 (reused as Vt after qkv)
    unsigned short* wqkvT = xb    + (size_t)MTOK * D_;      // 3072*1024
    unsigned short* woutT = wqkvT + (size_t)3 * D_ * D_;    // 1024*1024
    unsigned short* Qw    = woutT + (size_t)D_ * D_;        // 8192*1024
    unsigned short* Kw    = Qw    + (size_t)MTOK * D_;
    unsigned short* Vw    = Kw    + (size_t)MTOK * D_;
    unsigned short* attnb = Vw    + (size_t)MTOK * D_;
    unsigned short* Vt    = xb;   // alias: xb is dead after k_gemm_qkv

    k_conv_x<<<2048, 256, 0, stream>>>(x, xb, MTOK * D_ / 8);
    k_transpose_bf<<<(3 * D_ * (D_ / 8)) / 256, 256, 0, stream>>>(w_qkv, wqkvT, D_, 3 * D_);
    k_transpose_bf<<<(D_ * (D_ / 8)) / 256, 256, 0, stream>>>(w_out, woutT, D_, D_);
    k_gemm_qkv<<<1536, 256, 0, stream>>>(xb, wqkvT, b_qkv, Qw, Kw, Vw);
    k_transpose_v<<<2048, 256, 0, stream>>>(Vw, Vt);
    k_attn<<<512, 512, 0, stream>>>(Qw, Kw, Vt, attnb);
    k_gemm_proj<<<512, 256, 0, stream>>>(attnb, woutT, b_out, out);
}

// Round 19
// 197.583 us; speedup vs baseline: 1.0758x; 1.0758x over previous
//
#include <hip/hip_runtime.h>
#include <hip/hip_bf16.h>
#include <stdint.h>
#include <type_traits>

// CausalSelfAttention: B=4 S=2048 D=1024 H=16 hd=64
// Best-known assembly (R17): conv(x) -> QKV gemm (R10: 128x128, BK=32, global_load_lds)
//   -> V transpose -> flash attn v5 (paired q-tiles, 32x32 mfma, in-register P,
//      defer-max, end-combined lsum) -> out-proj gemm (dbuf)

#define B_   4
#define S_   2048
#define D_   1024
#define H_   16
#define HD_  64
#define MTOK (B_ * S_)   // 8192
#define BK   32
#define QSCALE 0.18033688011112042f   // 0.125 * log2(e)

typedef __attribute__((ext_vector_type(8))) short bfx8;
typedef __attribute__((ext_vector_type(4))) float fx4;
typedef __attribute__((ext_vector_type(16))) float fx16;

#define MAX3(a,b,c) fmaxf(fmaxf(a,b),c)

static __device__ __forceinline__ unsigned short f2bf(float f) {
    union { float f; uint32_t u; } v{f};
    uint32_t u = v.u;
    u += 0x7fffu + ((u >> 16) & 1u);   // RNE
    return (unsigned short)(u >> 16);
}

static __device__ __forceinline__ uint32_t cvtpk(float lo, float hi) {
    uint32_t r;
    asm volatile("v_cvt_pk_bf16_f32 %0, %1, %2" : "=v"(r) : "v"(lo), "v"(hi));
    return r;
}

// v_permlane32_swap_b32 (distinct operands only — R8 bug)
static __device__ __forceinline__ void pswap(uint32_t& a, uint32_t& b) {
    asm volatile("v_permlane32_swap_b32 %0, %1" : "+v"(a), "+v"(b));
}

// global -> LDS direct DMA, 16B/lane; LDS dest = wave-uniform base + lane*16
static __device__ __forceinline__ void gll16(const unsigned short* g, const unsigned short* l) {
    typedef const __attribute__((address_space(1))) void* gp_t;
    typedef __attribute__((address_space(3))) void* lp_t;
    __builtin_amdgcn_global_load_lds((gp_t)(uintptr_t)g, (lp_t)(uint32_t)(uintptr_t)l, 16, 0, 0);
}

// ---------------- convert x f32 -> bf16 ----------------
__global__ void k_conv_x(const float* __restrict__ x, unsigned short* __restrict__ xb, int n8) {
    int i = blockIdx.x * blockDim.x + threadIdx.x;
    int stride = gridDim.x * blockDim.x;
    for (; i < n8; i += stride) {
        const float4* p = (const float4*)(x + (size_t)i * 8);
        float4 a = p[0], b = p[1];
        bfx8 o;
        o[0]=f2bf(a.x); o[1]=f2bf(a.y); o[2]=f2bf(a.z); o[3]=f2bf(a.w);
        o[4]=f2bf(b.x); o[5]=f2bf(b.y); o[6]=f2bf(b.z); o[7]=f2bf(b.w);
        *(bfx8*)(xb + (size_t)i * 8) = o;
    }
}

// ---------------- transpose W [K][N] f32 -> Wt [N][K] bf16 ----------------
__global__ void k_transpose_bf(const float* __restrict__ w, unsigned short* __restrict__ wt,
                               int K, int N) {
    int idx = blockIdx.x * blockDim.x + threadIdx.x;
    int total = N * (K / 8);
    if (idx >= total) return;
    int n  = idx % N;
    int k0 = (idx / N) * 8;
    bfx8 o;
#pragma unroll
    for (int j = 0; j < 8; ++j) o[j] = f2bf(w[(size_t)(k0 + j) * N + n]);
    *(bfx8*)(wt + (size_t)n * K + k0) = o;
}

// ---------------- V transpose: Vw [bh][s][64] -> Vt [bh][64][s] ----------------
__global__ void k_transpose_v(const unsigned short* __restrict__ Vw,
                              unsigned short* __restrict__ Vt) {
    __shared__ unsigned short lds[64][72];
    const int bg = blockIdx.x;            // 2048 = 64 bh x 32 s-tiles
    const int bh = bg >> 5;
    const int st = (bg & 31) * 64;
    const int t = threadIdx.x;
#pragma unroll
    for (int j = 0; j < 2; ++j) {
        int c = t + 256 * j;
        int row = c >> 3, q = c & 7;
        *(bfx8*)&lds[row][q * 8] = *(const bfx8*)&Vw[((size_t)bh * S_ + st + row) * HD_ + q * 8];
    }
    __syncthreads();
#pragma unroll
    for (int j = 0; j < 2; ++j) {
        int c = t + 256 * j;
        int d = c >> 3, q = c & 7;
        bfx8 o;
#pragma unroll
        for (int e = 0; e < 8; ++e) o[e] = lds[q * 8 + e][d];
        *(bfx8*)&Vt[((size_t)bh * HD_ + d) * S_ + st + q * 8] = o;
    }
}

// ---------------- QKV GEMM: [8192,1024] x [1024,3072], BK=32, swapped mfma (R10) ----------------
__launch_bounds__(256)
__global__ void k_gemm_qkv(const unsigned short* __restrict__ A,
                           const unsigned short* __restrict__ Bt,
                           const float* __restrict__ bias,
                           unsigned short* __restrict__ Qw,
                           unsigned short* __restrict__ Kw,
                           unsigned short* __restrict__ Vw) {
    __shared__ unsigned short Al[128 * BK];   // 8KB, 64B rows
    __shared__ unsigned short Bl[128 * BK];
    const int wg = blockIdx.x;
    const int lin = (wg & 7) * 192 + (wg >> 3);
    const int ny = lin / 24, nx = lin - ny * 24;
    const int m0 = ny * 128;
    const int n0 = nx * 128;
    const int t = threadIdx.x;
    const int w = t >> 6, l = t & 63;
    const int wr = w >> 1, wc = w & 1;
    const int lr = l & 15, lg = l >> 4;
    const int srow = l >> 2;
    const int scol = (l & 3) * 8;
    fx4 acc[4][4] = {};

    for (int k0 = 0; k0 < D_; k0 += BK) {
        __syncthreads();
#pragma unroll
        for (int j = 0; j < 2; ++j) {
            int rb = j * 64 + w * 16;
            gll16(&A [(size_t)(m0 + rb + srow) * D_ + k0 + scol], &Al[rb * BK]);
            gll16(&Bt[(size_t)(n0 + rb + srow) * D_ + k0 + scol], &Bl[rb * BK]);
        }
        __syncthreads();
        bfx8 af[4], bf[4];
#pragma unroll
        for (int i = 0; i < 4; ++i) af[i] = *(const bfx8*)&Al[(wr * 64 + i * 16 + lr) * BK + lg * 8];
#pragma unroll
        for (int i = 0; i < 4; ++i) bf[i] = *(const bfx8*)&Bl[(wc * 64 + i * 16 + lr) * BK + lg * 8];
#pragma unroll
        for (int mi = 0; mi < 4; ++mi)
#pragma unroll
            for (int ni = 0; ni < 4; ++ni)
                acc[mi][ni] = __builtin_amdgcn_mfma_f32_16x16x32_bf16(bf[ni], af[mi], acc[mi][ni], 0, 0, 0);
    }

#pragma unroll
    for (int ni = 0; ni < 4; ++ni) {
        const int nn = n0 + wc * 64 + ni * 16 + lg * 4;
        const int mat = nn >> 10;
        const int h = (nn & 1023) >> 6, dd = nn & 63;
        const float4 bv = *(const float4*)&bias[nn];
        unsigned short* dst = (mat == 0) ? Qw : (mat == 1) ? Kw : Vw;
        const float sc = (mat == 0) ? QSCALE : 1.0f;
#pragma unroll
        for (int mi = 0; mi < 4; ++mi) {
            const int m = m0 + wr * 64 + mi * 16 + lr;
            const int b = m >> 11, s = m & 2047;
            const int bh = b * H_ + h;
            fx4 v = acc[mi][ni];
            float o0 = (v[0] + bv.x) * sc, o1 = (v[1] + bv.y) * sc;
            float o2 = (v[2] + bv.z) * sc, o3 = (v[3] + bv.w) * sc;
            uint2 u; u.x = cvtpk(o0, o1); u.y = cvtpk(o2, o3);
            *(uint2*)&dst[((size_t)bh * S_ + s) * HD_ + dd] = u;
        }
    }
}

// ---------------- flash attention v5 (32x32 mfma, in-register P, end-combined lsum) ----------------
// 8 waves: w0-3 = big tile (15-pi), w4-7 = small tile (pi); 32 q-rows/wave.
// Paired tiles -> every block = 34 uniform work units (dispatch-granularity balance).
__launch_bounds__(512, 4)
__global__ void k_attn(const unsigned short* __restrict__ Qw,
                       const unsigned short* __restrict__ Kw,
                       const unsigned short* __restrict__ Vt,
                       unsigned short* __restrict__ Ob) {
    __shared__ unsigned short Sh[4][64 * 64];   // [0,1]=K dbuf, [2,3]=V dbuf; rows 128B XOR-swizzled
    const int wg = blockIdx.x;                  // 512
    const int xcd = wg & 7, ix = wg >> 3;
    const int bh = xcd * 8 + (ix >> 3);
    const int pi = ix & 7;
    const int t = threadIdx.x;
    const int w = t >> 6, l = t & 63;
    const int lq = l & 31, hi = l >> 5;
    const int tile = (w < 4) ? (15 - pi) : pi;
    const int qr = tile * 128 + (w & 3) * 32;
    const int NT = 32 - 2 * pi;                 // always even

    const unsigned short* Qp = Qw + (size_t)bh * S_ * HD_;
    const unsigned short* Kp = Kw + (size_t)bh * S_ * HD_;
    const unsigned short* Vp = Vt + (size_t)bh * HD_ * S_;

    bfx8 qf[4];
#pragma unroll
    for (int kb = 0; kb < 4; ++kb)
        qf[kb] = *(const bfx8*)&Qp[(size_t)(qr + lq) * HD_ + kb * 16 + hi * 8];

    fx16 oacc[2] = {};
    float mrow = -1e30f, lsum = 0.f;            // own-half sum; combined once at end

    const int sid0 = t, sid1 = t + 512;
    const int srow0 = (sid0 & 511) >> 3, sq0 = sid0 & 7;
    const int srow1 = (sid1 & 511) >> 3, sq1 = sid1 & 7;
    const int soff0 = srow0 * 128 + ((sq0 * 16) ^ ((srow0 & 7) << 4));
    const int soff1 = srow1 * 128 + ((sq1 * 16) ^ ((srow1 & 7) << 4));

    auto step = [&](auto bufc, int tkv) {
        constexpr int BUF = decltype(bufc)::value;
        const int kv0 = tkv * 64;
        const bool pre = (tkv + 1 < NT);
        bfx8 sreg0, sreg1;
        if (pre) {
            const int kn = kv0 + 64;
            sreg0 = *(const bfx8*)&Kp[(size_t)(kn + srow0) * HD_ + sq0 * 8];
            sreg1 = *(const bfx8*)&Vp[(size_t)srow1 * S_ + kn + sq1 * 8];
        }
        if (kv0 <= qr + 31) {
            const char* Kb = (const char*)&Sh[BUF][0];
            const char* Vb = (const char*)&Sh[2 + BUF][0];
            const int sw = (lq & 7) << 4;
            fx16 s0 = {}, s1 = {};
            __builtin_amdgcn_s_setprio(1);
#pragma unroll
            for (int kb = 0; kb < 4; ++kb) {
                const int cb = kb * 32 + hi * 16;
                bfx8 k0 = *(const bfx8*)(Kb + lq * 128 + (cb ^ sw));
                bfx8 k1 = *(const bfx8*)(Kb + (32 + lq) * 128 + (cb ^ sw));
                s0 = __builtin_amdgcn_mfma_f32_32x32x16_bf16(k0, qf[kb], s0, 0, 0, 0);
                s1 = __builtin_amdgcn_mfma_f32_32x32x16_bf16(k1, qf[kb], s1, 0, 0, 0);
            }
            __builtin_amdgcn_s_setprio(0);
            if (kv0 + 63 > qr) {
                const int qrel = qr + lq - kv0;
#pragma unroll
                for (int r = 0; r < 16; ++r) {
                    const int kvo = (r & 3) + 8 * (r >> 2) + 4 * hi;
                    if (kvo > qrel)      s0[r] = -1e30f;
                    if (kvo + 32 > qrel) s1[r] = -1e30f;
                }
            }
            float a0 = MAX3(s0[0], s0[1], s0[2]);
            float a1 = MAX3(s0[3], s0[4], s0[5]);
            float a2 = MAX3(s0[6], s0[7], s0[8]);
            float a3 = MAX3(s0[9], s0[10], s0[11]);
            float a4 = MAX3(s0[12], s0[13], s0[14]);
            float a5 = MAX3(s0[15], s1[0], s1[1]);
            float a6 = MAX3(s1[2], s1[3], s1[4]);
            float a7 = MAX3(s1[5], s1[6], s1[7]);
            float a8 = MAX3(s1[8], s1[9], s1[10]);
            float a9 = MAX3(s1[11], s1[12], s1[13]);
            float aA = fmaxf(s1[14], s1[15]);
            float b0 = MAX3(a0, a1, a2);
            float b1 = MAX3(a3, a4, a5);
            float b2 = MAX3(a6, a7, a8);
            float b3 = fmaxf(a9, aA);
            float mx = MAX3(fmaxf(b0, b1), b2, b3);
            mx = fmaxf(mx, __shfl_xor(mx, 32));    // mx shared across partners -> al identical
            if (!__all(mx <= mrow + 8.f)) {
                const float mnew = fmaxf(mrow, mx);
                const float al = exp2f(mrow - mnew);
                mrow = mnew;
#pragma unroll
                for (int r = 0; r < 16; ++r) { oacc[0][r] *= al; oacc[1][r] *= al; }
                lsum *= al;
            }
            uint32_t pk0[8], pk1[8];
            float ps = 0.f;
#pragma unroll
            for (int j = 0; j < 8; ++j) {
                float p0 = exp2f(s0[2 * j] - mrow), p1 = exp2f(s0[2 * j + 1] - mrow);
                float p2 = exp2f(s1[2 * j] - mrow), p3 = exp2f(s1[2 * j + 1] - mrow);
                ps += (p0 + p1) + (p2 + p3);
                pk0[j] = cvtpk(p0, p1);
                pk1[j] = cvtpk(p2, p3);
            }
            lsum += ps;                            // own-half only; combine at end
            __builtin_amdgcn_s_setprio(1);
#pragma unroll
            for (int sl = 0; sl < 4; ++sl) {
                const uint32_t* pk = (sl < 2) ? pk0 : pk1;
                const int s = sl & 1;
                uint32_t w0 = pk[4 * s], w1 = pk[4 * s + 1], w2 = pk[4 * s + 2], w3 = pk[4 * s + 3];
                pswap(w0, w2);
                pswap(w1, w3);
                union { uint32_t u[4]; bfx8 v; } pf;
                pf.u[0] = w0; pf.u[1] = w1; pf.u[2] = w2; pf.u[3] = w3;
                const int cb = sl * 32 + hi * 16;
                bfx8 v0 = *(const bfx8*)(Vb + lq * 128 + (cb ^ sw));
                bfx8 v1 = *(const bfx8*)(Vb + (32 + lq) * 128 + (cb ^ sw));
                oacc[0] = __builtin_amdgcn_mfma_f32_32x32x16_bf16(v0, pf.v, oacc[0], 0, 0, 0);
                oacc[1] = __builtin_amdgcn_mfma_f32_32x32x16_bf16(v1, pf.v, oacc[1], 0, 0, 0);
            }
            __builtin_amdgcn_s_setprio(0);
        }
        if (pre) {
            *(bfx8*)((char*)&Sh[BUF ^ 1][0] + soff0) = sreg0;
            *(bfx8*)((char*)&Sh[2 + (BUF ^ 1)][0] + soff1) = sreg1;
        }
    };

    {
        bfx8 s0 = *(const bfx8*)&Kp[(size_t)srow0 * HD_ + sq0 * 8];
        bfx8 s1 = *(const bfx8*)&Vp[(size_t)srow1 * S_ + sq1 * 8];
        *(bfx8*)((char*)&Sh[0][0] + soff0) = s0;
        *(bfx8*)((char*)&Sh[2][0] + soff1) = s1;
    }
    __syncthreads();

    for (int tkv = 0; tkv < NT; tkv += 2) {
        step(std::integral_constant<int, 0>{}, tkv);
        __syncthreads();
        step(std::integral_constant<int, 1>{}, tkv + 1);
        __syncthreads();
    }

    lsum += __shfl_xor(lsum, 32);               // combine halves once
    const int b = bh >> 4, h = bh & 15;
    const float iv = __builtin_amdgcn_rcpf(lsum);
    unsigned short* orow = Ob + ((size_t)b * S_ + qr + lq) * D_ + h * 64;
#pragma unroll
    for (int db = 0; db < 2; ++db)
#pragma unroll
        for (int rq = 0; rq < 4; ++rq) {
            uint2 u;
            u.x = cvtpk(oacc[db][rq * 4 + 0] * iv, oacc[db][rq * 4 + 1] * iv);
            u.y = cvtpk(oacc[db][rq * 4 + 2] * iv, oacc[db][rq * 4 + 3] * iv);
            *(uint2*)&orow[db * 32 + rq * 8 + hi * 4] = u;
        }
}

// ---------------- out-proj GEMM: [8192,1024] x [1024,1024] + bias, f32 out, dbuf ----------------
__launch_bounds__(256)
__global__ void k_gemm_proj(const unsigned short* __restrict__ A,
                            const unsigned short* __restrict__ Bt,
                            const float* __restrict__ bias,
                            float* __restrict__ out) {
    __shared__ unsigned short Al[2][128 * BK];
    __shared__ unsigned short Bl[2][128 * BK];
    const int wg = blockIdx.x;                 // 512 blocks: 8 n x 64 m
    const int lin = (wg & 7) * 64 + (wg >> 3);
    const int ny = lin >> 3, nx = lin & 7;
    const int m0 = ny * 128;
    const int n0 = nx * 128;
    const int t = threadIdx.x;
    const int w = t >> 6, l = t & 63;
    const int wr = w >> 1, wc = w & 1;
    const int lr = l & 15, lg = l >> 4;
    const int srow = l >> 2;
    const int scol = (l & 3) * 8;
    fx4 acc[4][4] = {};

    auto stage = [&](int k0, int buf) {
#pragma unroll
        for (int j = 0; j < 2; ++j) {
            int rb = j * 64 + w * 16;
            gll16(&A [(size_t)(m0 + rb + srow) * D_ + k0 + scol], &Al[buf][rb * BK]);
            gll16(&Bt[(size_t)(n0 + rb + srow) * D_ + k0 + scol], &Bl[buf][rb * BK]);
        }
    };
    auto compute = [&](auto bufc) {
        constexpr int BUF = decltype(bufc)::value;
        bfx8 af[4], bf[4];
#pragma unroll
        for (int i = 0; i < 4; ++i) af[i] = *(const bfx8*)&Al[BUF][(wr * 64 + i * 16 + lr) * BK + lg * 8];
#pragma unroll
        for (int i = 0; i < 4; ++i) bf[i] = *(const bfx8*)&Bl[BUF][(wc * 64 + i * 16 + lr) * BK + lg * 8];
#pragma unroll
        for (int mi = 0; mi < 4; ++mi)
#pragma unroll
            for (int ni = 0; ni < 4; ++ni)
                acc[mi][ni] = __builtin_amdgcn_mfma_f32_16x16x32_bf16(bf[ni], af[mi], acc[mi][ni], 0, 0, 0);
    };

    stage(0, 0);
    __syncthreads();
    for (int k0 = 0; k0 < D_; k0 += 2 * BK) {
        if (k0 + BK < D_) stage(k0 + BK, 1);
        compute(std::integral_constant<int, 0>{});
        __syncthreads();
        if (k0 + 2 * BK < D_) stage(k0 + 2 * BK, 0);
        compute(std::integral_constant<int, 1>{});
        __syncthreads();
    }
#pragma unroll
    for (int ni = 0; ni < 4; ++ni) {
        const int nn = n0 + wc * 64 + ni * 16 + lg * 4;
        const float4 bv = *(const float4*)&bias[nn];
#pragma unroll
        for (int mi = 0; mi < 4; ++mi) {
            const int m = m0 + wr * 64 + mi * 16 + lr;
            fx4 v = acc[mi][ni];
            float4 o; o.x = v[0] + bv.x; o.y = v[1] + bv.y; o.z = v[2] + bv.z; o.w = v[3] + bv.w;
            *(float4*)&out[(size_t)m * D_ + nn] = o;
        }
    }
}

extern "C" void kernel_launch(void* const* d_in, const int* in_sizes, int n_in,
                              void* d_out, int out_size, void* d_ws, size_t ws_size,
                              hipStream_t stream) {
    const float* x     = (const float*)d_in[0];
    const float* w_qkv = (const float*)d_in[1];
    const float* b_qkv = (const float*)d_in[2];
    const float* w_out = (const float*)d_in[3];
    const float* b_out = (const float*)d_in[4];
    float* out = (float*)d_out;

    unsigned short* xb    = (unsigned short*)d_ws;          // 8192*1024 (reused as Vt after qkv)
    unsigned short* wqkvT = xb    + (size_t)MTOK * D_;      // 3072*1024
    unsigned short* woutT = wqkvT + (size_t)3 * D_ * D_;    // 1024*1024
    unsigned short* Qw    = woutT + (size_t)D_ * D_;        // 8192*1024
    unsigned short* Kw    = Qw    + (size_t)MTOK * D_;
    unsigned short* Vw    = Kw    + (size_t)MTOK * D_;
    unsigned short* attnb = Vw    + (size_t)MTOK * D_;
    unsigned short* Vt    = xb;   // alias: xb is dead after k_gemm_qkv

    k_conv_x<<<2048, 256, 0, stream>>>(x, xb, MTOK * D_ / 8);
    k_transpose_bf<<<(3 * D_ * (D_ / 8)) / 256, 256, 0, stream>>>(w_qkv, wqkvT, D_, 3 * D_);
    k_transpose_bf<<<(D_ * (D_ / 8)) / 256, 256, 0, stream>>>(w_out, woutT, D_, D_);
    k_gemm_qkv<<<1536, 256, 0, stream>>>(xb, wqkvT, b_qkv, Qw, Kw, Vw);
    k_transpose_v<<<2048, 256, 0, stream>>>(Vw, Vt);
    k_attn<<<512, 512, 0, stream>>>(Qw, Kw, Vt, attnb);
    k_gemm_proj<<<512, 256, 0, stream>>>(attnb, woutT, b_out, out);
}